// Round 1
// baseline (2273.626 us; speedup 1.0000x reference)
//
#include <hip/hip_runtime.h>

constexpr int H_  = 64;   // hidden
constexpr int DIN = 32;   // atom feature dim
constexpr int DE  = 16;   // edge feature dim
#define SLOPE 0.2f

__device__ __forceinline__ float sigm_(float x){ return 1.0f/(1.0f+__expf(-x)); }
__device__ __forceinline__ float tanh_(float x){ float e=__expf(2.0f*x); return 1.0f - 2.0f/(e+1.0f); }

// dst[b][c][r] = src[b][r][c]
__global__ void k_transpose(const float* __restrict__ src, float* __restrict__ dst, int B,int R,int C){
  int id = blockIdx.x*blockDim.x+threadIdx.x;
  if (id >= B*R*C) return;
  int rc=R*C, b=id/rc, rem=id-b*rc, r=rem/C, c=rem-r*C;
  dst[b*rc + c*R + r] = src[id];
}

// ve[l][k] = sum_j conv_We[l][k][j] * att_e[l][j]
__global__ void k_ve(const float* __restrict__ We, const float* __restrict__ ae, float* __restrict__ ve){
  int id = blockIdx.x*blockDim.x+threadIdx.x;
  if (id >= 3*H_) return;
  int l=id/H_, k=id-l*H_;
  const float* w = We + (size_t)(l*H_+k)*H_;
  const float* a = ae + l*H_;
  float s=0.f;
  #pragma unroll
  for(int j=0;j<H_;j++) s += w[j]*a[j];
  ve[id]=s;
}

__global__ void k_init(int* __restrict__ deg, float* __restrict__ ssum, int N){
  int n = blockIdx.x*blockDim.x+threadIdx.x;
  if (n>=N) return;
  deg[n]=1;                 // self-loop
  ssum[n]=0.f; ssum[N+n]=0.f; ssum[2*N+n]=0.f;
}

// xi = relu(x @ w_node + b_node), thread per node, wT transposed [64][32]
__global__ void k_node_mlp(const float* __restrict__ x, const float* __restrict__ wT,
                           const float* __restrict__ b, float* __restrict__ xi, int N){
  int n = blockIdx.x*blockDim.x+threadIdx.x;
  if (n>=N) return;
  float xv[DIN];
  const float4* xr = (const float4*)(x + (size_t)n*DIN);
  #pragma unroll
  for(int q=0;q<DIN/4;q++){ float4 v=xr[q]; xv[4*q]=v.x; xv[4*q+1]=v.y; xv[4*q+2]=v.z; xv[4*q+3]=v.w; }
  for(int j0=0;j0<H_;j0+=4){
    float o[4];
    #pragma unroll
    for(int jj=0;jj<4;jj++){
      int j=j0+jj;
      const float* wr = wT + j*DIN;   // uniform -> s_load
      float acc = b[j];
      #pragma unroll
      for(int k=0;k<DIN;k++) acc += xv[k]*wr[k];
      o[jj] = fmaxf(acc,0.f);
    }
    *(float4*)(xi + (size_t)n*H_ + j0) = make_float4(o[0],o[1],o[2],o[3]);
  }
}

// per-edge: ea = relu(attr@w_edge+b); escore[l][e] = ea . ve[l];
// accumulate per-dst score sums (for self-loop mean) + degree histogram
__global__ void k_edge_scores(const float* __restrict__ attr, const float* __restrict__ weT,
                              const float* __restrict__ be, const float* __restrict__ ve,
                              const int* __restrict__ dst, float* __restrict__ escore,
                              float* __restrict__ ssum, int* __restrict__ deg,
                              int E, int EN, int N){
  int e = blockIdx.x*blockDim.x+threadIdx.x;
  if (e>=E) return;
  float av[DE];
  const float4* ar = (const float4*)(attr + (size_t)e*DE);
  #pragma unroll
  for(int q=0;q<DE/4;q++){ float4 v=ar[q]; av[4*q]=v.x; av[4*q+1]=v.y; av[4*q+2]=v.z; av[4*q+3]=v.w; }
  float s0=0.f,s1=0.f,s2=0.f;
  for(int j=0;j<H_;j++){
    const float* wr = weT + j*DE;     // uniform
    float acc = be[j];
    #pragma unroll
    for(int k=0;k<DE;k++) acc += av[k]*wr[k];
    acc = fmaxf(acc,0.f);
    s0 += acc*ve[j]; s1 += acc*ve[H_+j]; s2 += acc*ve[2*H_+j];
  }
  escore[e] = s0; escore[EN+e] = s1; escore[2*EN+e] = s2;
  int d = dst[e];
  atomicAdd(&ssum[d],     s0);
  atomicAdd(&ssum[N+d],   s1);
  atomicAdd(&ssum[2*N+d], s2);
  atomicAdd(&deg[d], 1);
}

// self-loop scores: mean of incoming relu'd ea, dotted with ve (linear => mean of scores)
__global__ void k_selfloop(const float* __restrict__ ssum, const int* __restrict__ deg,
                           float* __restrict__ escore, int E, int EN, int N){
  int n = blockIdx.x*blockDim.x+threadIdx.x;
  if (n>=N) return;
  float c = (float)(deg[n]-1);
  float inv = (c>0.f) ? 1.0f/c : 0.0f;
  escore[E+n]        = ssum[n]*inv;
  escore[EN+E+n]     = ssum[N+n]*inv;
  escore[2*EN+E+n]   = ssum[2*N+n]*inv;
}

// single-block exclusive scan of deg -> off (and cur copy); off[N] = total
__global__ void k_scan(const int* __restrict__ deg, int* __restrict__ off, int* __restrict__ cur, int N){
  __shared__ int part[1024];
  int tid = threadIdx.x;
  int chunk = (N + 1023)>>10;
  int base = tid*chunk;
  int s=0;
  for(int i=0;i<chunk;i++){ int idx=base+i; if(idx<N) s+=deg[idx]; }
  part[tid]=s;
  __syncthreads();
  for(int d=1; d<1024; d<<=1){
    int v = 0;
    if (tid>=d) v = part[tid-d];
    __syncthreads();
    if (tid>=d) part[tid]+=v;
    __syncthreads();
  }
  int excl = (tid==0)?0:part[tid-1];
  for(int i=0;i<chunk;i++){
    int idx=base+i;
    if(idx<N){ off[idx]=excl; cur[idx]=excl; excl+=deg[idx]; }
  }
  if (tid==1023) off[N]=excl;
}

__global__ void k_fill(const int* __restrict__ dst, int* __restrict__ cur, int* __restrict__ eid, int E, int N){
  int e = blockIdx.x*blockDim.x+threadIdx.x;
  if (e>=E+N) return;
  int d = (e<E) ? dst[e] : (e-E);
  int p = atomicAdd(&cur[d],1);
  eid[p] = e;
}

// h = xi @ conv_W[l]; s_sc = h.att_s; d_sc = h.att_d
__global__ void k_linear_h(const float* __restrict__ xi, const float* __restrict__ wT,
                           const float* __restrict__ atts, const float* __restrict__ attd,
                           float* __restrict__ h, float* __restrict__ ssc, float* __restrict__ dsc, int N){
  int n = blockIdx.x*blockDim.x+threadIdx.x;
  if (n>=N) return;
  float xv[H_];
  const float4* xr = (const float4*)(xi + (size_t)n*H_);
  #pragma unroll
  for(int q=0;q<H_/4;q++){ float4 v=xr[q]; xv[4*q]=v.x; xv[4*q+1]=v.y; xv[4*q+2]=v.z; xv[4*q+3]=v.w; }
  float sa=0.f, da=0.f;
  for(int j0=0;j0<H_;j0+=4){
    float o[4];
    #pragma unroll
    for(int jj=0;jj<4;jj++){
      int j=j0+jj;
      const float* wr = wT + j*H_;   // uniform
      float acc=0.f;
      #pragma unroll
      for(int k=0;k<H_;k++) acc += xv[k]*wr[k];
      o[jj]=acc;
      sa += acc*atts[j]; da += acc*attd[j];
    }
    *(float4*)(h + (size_t)n*H_ + j0) = make_float4(o[0],o[1],o[2],o[3]);
  }
  ssc[n]=sa; dsc[n]=da;
}

// wave per node: segment softmax + weighted aggregation
__global__ void k_gat(const float* __restrict__ h, const float* __restrict__ ssc,
                      const float* __restrict__ dsc, const float* __restrict__ escore,
                      const int* __restrict__ off, const int* __restrict__ eid,
                      const int* __restrict__ srcarr, const float* __restrict__ bias,
                      float* __restrict__ hgat, int E, int N){
  int gid = blockIdx.x*blockDim.x + threadIdx.x;
  int node = gid >> 6;
  int lane = threadIdx.x & 63;
  if (node >= N) return;
  int e0 = off[node], e1 = off[node+1];
  float dval = dsc[node];
  // pass 1: max over incoming edges (lane-parallel)
  float mx = -1e30f;
  for (int p = e0 + lane; p < e1; p += 64) {
    int e = eid[p];
    int s = (e < E) ? srcarr[e] : (e - E);
    float a = ssc[s] + dval + escore[e];
    a = (a > 0.f) ? a : SLOPE*a;
    mx = fmaxf(mx, a);
  }
  #pragma unroll
  for (int d=32; d; d>>=1) mx = fmaxf(mx, __shfl_xor(mx, d));
  // pass 2: serial over edges, lanes = feature dims
  float acc = 0.f, den = 0.f;
  for (int p = e0; p < e1; p++) {
    int e = eid[p];
    int s = (e < E) ? srcarr[e] : (e - E);
    float a = ssc[s] + dval + escore[e];
    a = (a > 0.f) ? a : SLOPE*a;
    float ex = __expf(a - mx);
    den += ex;
    acc += ex * h[(size_t)s*H_ + lane];
  }
  hgat[(size_t)node*H_ + lane] = fmaxf(acc/den + bias[lane], 0.f);
}

// fused GRU cell + relu, in-place xi update. WihT/WhhT are [192][64].
__global__ void __launch_bounds__(256) k_gru(const float* __restrict__ hg, float* __restrict__ xi,
                     const float* __restrict__ WihT, const float* __restrict__ WhhT,
                     const float* __restrict__ bih, const float* __restrict__ bhh, int N){
  int n = blockIdx.x*blockDim.x+threadIdx.x;
  if (n>=N) return;
  float hv[H_], xv[H_];
  const float4* hr = (const float4*)(hg + (size_t)n*H_);
  const float4* xr = (const float4*)(xi + (size_t)n*H_);
  #pragma unroll
  for(int q=0;q<H_/4;q++){
    float4 v=hr[q]; hv[4*q]=v.x; hv[4*q+1]=v.y; hv[4*q+2]=v.z; hv[4*q+3]=v.w;
    float4 u=xr[q]; xv[4*q]=u.x; xv[4*q+1]=u.y; xv[4*q+2]=u.z; xv[4*q+3]=u.w;
  }
  for(int j0=0;j0<H_;j0+=4){
    float4 xin = *(const float4*)(xi + (size_t)n*H_ + j0);   // blend value (avoid dyn reg idx)
    const float* xp = (const float*)&xin;
    float o[4];
    #pragma unroll
    for(int jj=0;jj<4;jj++){
      int j=j0+jj;
      float gir=bih[j], giz=bih[H_+j], gin=bih[2*H_+j];
      float ghr=bhh[j], ghz=bhh[H_+j], ghn=bhh[2*H_+j];
      const float* wir = WihT + (size_t)j*H_;
      const float* wiz = WihT + (size_t)(H_+j)*H_;
      const float* win = WihT + (size_t)(2*H_+j)*H_;
      const float* whr = WhhT + (size_t)j*H_;
      const float* whz = WhhT + (size_t)(H_+j)*H_;
      const float* whn = WhhT + (size_t)(2*H_+j)*H_;
      #pragma unroll
      for(int k=0;k<H_;k++){
        float hk=hv[k], xk=xv[k];
        gir += hk*wir[k]; giz += hk*wiz[k]; gin += hk*win[k];
        ghr += xk*whr[k]; ghz += xk*whz[k]; ghn += xk*whn[k];
      }
      float r = sigm_(gir+ghr);
      float z = sigm_(giz+ghz);
      float nn = tanh_(gin + r*ghn);
      o[jj] = fmaxf((1.f-z)*nn + z*xp[jj], 0.f);
    }
    *(float4*)(xi + (size_t)n*H_ + j0) = make_float4(o[0],o[1],o[2],o[3]);
  }
}

__global__ void k_pool_init(float* __restrict__ out, const float* __restrict__ b_out, int G){
  int g = blockIdx.x*blockDim.x+threadIdx.x;
  if (g<G) out[g] = b_out[0];
}

__global__ void k_pool(const float* __restrict__ xi, const float* __restrict__ wout,
                       const int* __restrict__ batch, float* __restrict__ out, int N){
  int n = blockIdx.x*blockDim.x+threadIdx.x;
  if (n>=N) return;
  float acc=0.f;
  const float4* xr=(const float4*)(xi + (size_t)n*H_);
  #pragma unroll
  for(int q=0;q<H_/4;q++){
    float4 v=xr[q];
    acc += v.x*wout[4*q] + v.y*wout[4*q+1] + v.z*wout[4*q+2] + v.w*wout[4*q+3];
  }
  atomicAdd(&out[batch[n]], acc);
}

extern "C" void kernel_launch(void* const* d_in, const int* in_sizes, int n_in,
                              void* d_out, int out_size, void* d_ws, size_t ws_size,
                              hipStream_t stream){
  const float* x       = (const float*)d_in[0];
  const float* eattr   = (const float*)d_in[1];
  const float* w_node  = (const float*)d_in[2];
  const float* b_node  = (const float*)d_in[3];
  const float* w_edge  = (const float*)d_in[4];
  const float* b_edge  = (const float*)d_in[5];
  const float* conv_W  = (const float*)d_in[6];
  const float* conv_We = (const float*)d_in[7];
  const float* att_s   = (const float*)d_in[8];
  const float* att_d   = (const float*)d_in[9];
  const float* att_e   = (const float*)d_in[10];
  const float* conv_b  = (const float*)d_in[11];
  const float* gWih    = (const float*)d_in[12];
  const float* gWhh    = (const float*)d_in[13];
  const float* gbih    = (const float*)d_in[14];
  const float* gbhh    = (const float*)d_in[15];
  const float* w_out   = (const float*)d_in[16];
  const float* b_out   = (const float*)d_in[17];
  const int*   eidx    = (const int*)d_in[18];
  const int*   batch   = (const int*)d_in[19];
  float* out = (float*)d_out;

  int N = in_sizes[0]/DIN;
  int E = in_sizes[1]/DE;
  int G = out_size;
  int EN = E + N;
  const int* src = eidx;
  const int* dst = eidx + E;

  char* p = (char*)d_ws;
  auto carve = [&](size_t bytes)->void*{ void* r=(void*)p; p += (bytes+255)&~(size_t)255; return r; };
  float* xi    = (float*)carve((size_t)N*H_*4);
  float* hbuf  = (float*)carve((size_t)N*H_*4);
  float* hgat  = (float*)carve((size_t)N*H_*4);
  float* ssc   = (float*)carve((size_t)N*4);
  float* dsc   = (float*)carve((size_t)N*4);
  float* escore= (float*)carve((size_t)3*EN*4);
  float* ssum  = (float*)carve((size_t)3*N*4);
  int*   deg   = (int*)carve((size_t)N*4);
  int*   off   = (int*)carve((size_t)(N+1)*4);
  int*   cur   = (int*)carve((size_t)(N+1)*4);
  int*   eid   = (int*)carve((size_t)EN*4);
  float* wnT   = (float*)carve((size_t)DIN*H_*4);
  float* weT   = (float*)carve((size_t)DE*H_*4);
  float* cWT   = (float*)carve((size_t)3*H_*H_*4);
  float* WihT  = (float*)carve((size_t)3*H_*3*H_*4);
  float* WhhT  = (float*)carve((size_t)3*H_*3*H_*4);
  float* ve    = (float*)carve((size_t)3*H_*4);

  auto cdiv=[](int a,int b){return (a+b-1)/b;};

  k_transpose<<<cdiv(DIN*H_,256),256,0,stream>>>(w_node, wnT, 1, DIN, H_);
  k_transpose<<<cdiv(DE*H_,256),256,0,stream>>>(w_edge, weT, 1, DE, H_);
  k_transpose<<<cdiv(3*H_*H_,256),256,0,stream>>>(conv_W, cWT, 3, H_, H_);
  k_transpose<<<cdiv(3*H_*3*H_,256),256,0,stream>>>(gWih, WihT, 3, H_, 3*H_);
  k_transpose<<<cdiv(3*H_*3*H_,256),256,0,stream>>>(gWhh, WhhT, 3, H_, 3*H_);
  k_ve<<<1,3*H_,0,stream>>>(conv_We, att_e, ve);

  k_init<<<cdiv(N,256),256,0,stream>>>(deg, ssum, N);
  k_node_mlp<<<cdiv(N,256),256,0,stream>>>(x, wnT, b_node, xi, N);
  k_edge_scores<<<cdiv(E,256),256,0,stream>>>(eattr, weT, b_edge, ve, dst, escore, ssum, deg, E, EN, N);
  k_selfloop<<<cdiv(N,256),256,0,stream>>>(ssum, deg, escore, E, EN, N);
  k_scan<<<1,1024,0,stream>>>(deg, off, cur, N);
  k_fill<<<cdiv(EN,256),256,0,stream>>>(dst, cur, eid, E, N);

  for (int l=0; l<3; l++){
    k_linear_h<<<cdiv(N,256),256,0,stream>>>(xi, cWT + (size_t)l*H_*H_, att_s + l*H_, att_d + l*H_,
                                             hbuf, ssc, dsc, N);
    k_gat<<<cdiv(N*64,256),256,0,stream>>>(hbuf, ssc, dsc, escore + (size_t)l*EN, off, eid, src,
                                           conv_b + l*H_, hgat, E, N);
    k_gru<<<cdiv(N,256),256,0,stream>>>(hgat, xi, WihT + (size_t)l*3*H_*H_, WhhT + (size_t)l*3*H_*H_,
                                        gbih + l*3*H_, gbhh + l*3*H_, N);
  }

  k_pool_init<<<cdiv(G,256),256,0,stream>>>(out, b_out, G);
  k_pool<<<cdiv(N,256),256,0,stream>>>(xi, w_out, batch, out, N);
}

// Round 2
// 1955.609 us; speedup vs baseline: 1.1626x; 1.1626x over previous
//
#include <hip/hip_runtime.h>

constexpr int H_  = 64;   // hidden
constexpr int DIN = 32;   // atom feature dim
constexpr int DE  = 16;   // edge feature dim
#define SLOPE 0.2f

__device__ __forceinline__ float sigm_(float x){ return 1.0f/(1.0f+__expf(-x)); }
__device__ __forceinline__ float tanh_(float x){ float e=__expf(2.0f*x); return 1.0f - 2.0f/(e+1.0f); }

// dst[b][c][r] = src[b][r][c]
__global__ void k_transpose(const float* __restrict__ src, float* __restrict__ dst, int B,int R,int C){
  int id = blockIdx.x*blockDim.x+threadIdx.x;
  if (id >= B*R*C) return;
  int rc=R*C, b=id/rc, rem=id-b*rc, r=rem/C, c=rem-r*C;
  dst[b*rc + c*R + r] = src[id];
}

// ve[l][k] = sum_j conv_We[l][k][j] * att_e[l][j]
__global__ void k_ve(const float* __restrict__ We, const float* __restrict__ ae, float* __restrict__ ve){
  int id = blockIdx.x*blockDim.x+threadIdx.x;
  if (id >= 3*H_) return;
  int l=id/H_, k=id-l*H_;
  const float* w = We + (size_t)(l*H_+k)*H_;
  const float* a = ae + l*H_;
  float s=0.f;
  #pragma unroll
  for(int j=0;j<H_;j++) s += w[j]*a[j];
  ve[id]=s;
}

__global__ void k_init(int* __restrict__ deg, float* __restrict__ ssum, int N){
  int n = blockIdx.x*blockDim.x+threadIdx.x;
  if (n>=N) return;
  deg[n]=1;                 // self-loop
  ssum[n]=0.f; ssum[N+n]=0.f; ssum[2*N+n]=0.f;
}

// xi = relu(x @ w_node + b_node), thread per node, wT transposed [64][32]
__global__ void k_node_mlp(const float* __restrict__ x, const float* __restrict__ wT,
                           const float* __restrict__ b, float* __restrict__ xi, int N){
  int n = blockIdx.x*blockDim.x+threadIdx.x;
  if (n>=N) return;
  float xv[DIN];
  const float4* xr = (const float4*)(x + (size_t)n*DIN);
  #pragma unroll
  for(int q=0;q<DIN/4;q++){ float4 v=xr[q]; xv[4*q]=v.x; xv[4*q+1]=v.y; xv[4*q+2]=v.z; xv[4*q+3]=v.w; }
  for(int j0=0;j0<H_;j0+=4){
    float o[4];
    #pragma unroll
    for(int jj=0;jj<4;jj++){
      int j=j0+jj;
      const float* wr = wT + j*DIN;   // uniform -> s_load
      float acc = b[j];
      #pragma unroll
      for(int k=0;k<DIN;k++) acc += xv[k]*wr[k];
      o[jj] = fmaxf(acc,0.f);
    }
    *(float4*)(xi + (size_t)n*H_ + j0) = make_float4(o[0],o[1],o[2],o[3]);
  }
}

// per-edge: ea = relu(attr@w_edge+b); escore[l][e] = ea . ve[l];
// accumulate per-dst score sums (for self-loop mean) + degree histogram
__global__ void k_edge_scores(const float* __restrict__ attr, const float* __restrict__ weT,
                              const float* __restrict__ be, const float* __restrict__ ve,
                              const int* __restrict__ dst, float* __restrict__ escore,
                              float* __restrict__ ssum, int* __restrict__ deg,
                              int E, int EN, int N){
  int e = blockIdx.x*blockDim.x+threadIdx.x;
  if (e>=E) return;
  float av[DE];
  const float4* ar = (const float4*)(attr + (size_t)e*DE);
  #pragma unroll
  for(int q=0;q<DE/4;q++){ float4 v=ar[q]; av[4*q]=v.x; av[4*q+1]=v.y; av[4*q+2]=v.z; av[4*q+3]=v.w; }
  float s0=0.f,s1=0.f,s2=0.f;
  for(int j=0;j<H_;j++){
    const float* wr = weT + j*DE;     // uniform
    float acc = be[j];
    #pragma unroll
    for(int k=0;k<DE;k++) acc += av[k]*wr[k];
    acc = fmaxf(acc,0.f);
    s0 += acc*ve[j]; s1 += acc*ve[H_+j]; s2 += acc*ve[2*H_+j];
  }
  escore[e] = s0; escore[EN+e] = s1; escore[2*EN+e] = s2;
  int d = dst[e];
  atomicAdd(&ssum[d],     s0);
  atomicAdd(&ssum[N+d],   s1);
  atomicAdd(&ssum[2*N+d], s2);
  atomicAdd(&deg[d], 1);
}

// self-loop scores: mean of incoming relu'd ea, dotted with ve (linear => mean of scores)
__global__ void k_selfloop(const float* __restrict__ ssum, const int* __restrict__ deg,
                           float* __restrict__ escore, int E, int EN, int N){
  int n = blockIdx.x*blockDim.x+threadIdx.x;
  if (n>=N) return;
  float c = (float)(deg[n]-1);
  float inv = (c>0.f) ? 1.0f/c : 0.0f;
  escore[E+n]        = ssum[n]*inv;
  escore[EN+E+n]     = ssum[N+n]*inv;
  escore[2*EN+E+n]   = ssum[2*N+n]*inv;
}

// ---- hierarchical scan of deg -> off (exclusive), cur copy ----
__global__ void k_bsum(const int* __restrict__ deg, int* __restrict__ bsum, int N){
  int i = blockIdx.x*256 + threadIdx.x;
  int v = (i<N) ? deg[i] : 0;
  #pragma unroll
  for(int d=32; d; d>>=1) v += __shfl_xor(v, d);
  __shared__ int sh[4];
  if ((threadIdx.x&63)==0) sh[threadIdx.x>>6] = v;
  __syncthreads();
  if (threadIdx.x==0) bsum[blockIdx.x] = sh[0]+sh[1]+sh[2]+sh[3];
}

// single block, NB <= 1024: exclusive scan of block sums; also write off[N]=EN
__global__ void k_bscan(const int* __restrict__ bsum, int* __restrict__ boff, int NB,
                        int* __restrict__ offN, int EN){
  __shared__ int sh[1024];
  int tid = threadIdx.x;
  int v = (tid<NB) ? bsum[tid] : 0;
  sh[tid] = v;
  __syncthreads();
  for(int d=1; d<1024; d<<=1){
    int t = 0;
    if (tid>=d) t = sh[tid-d];
    __syncthreads();
    if (tid>=d) sh[tid] += t;
    __syncthreads();
  }
  if (tid<NB) boff[tid] = sh[tid] - v;  // exclusive
  if (tid==0) offN[0] = EN;
}

__global__ void k_scan_fin(const int* __restrict__ deg, const int* __restrict__ boff,
                           int* __restrict__ off, int* __restrict__ cur, int N){
  __shared__ int sh[256];
  int i = blockIdx.x*256 + threadIdx.x;
  int v = (i<N) ? deg[i] : 0;
  sh[threadIdx.x] = v;
  __syncthreads();
  for(int d=1; d<256; d<<=1){
    int t = 0;
    if (threadIdx.x>=d) t = sh[threadIdx.x-d];
    __syncthreads();
    if (threadIdx.x>=d) sh[threadIdx.x] += t;
    __syncthreads();
  }
  if (i<N){
    int e = boff[blockIdx.x] + sh[threadIdx.x] - v;
    off[i] = e; cur[i] = e;
  }
}

__global__ void k_fill(const int* __restrict__ dst, int* __restrict__ cur, int* __restrict__ eid, int E, int N){
  int e = blockIdx.x*blockDim.x+threadIdx.x;
  if (e>=E+N) return;
  int d = (e<E) ? dst[e] : (e-E);
  int p = atomicAdd(&cur[d],1);
  eid[p] = e;
}

// h = xi @ conv_W[l]; ssc = h.att_s; dsc = h.att_d
// 2 threads per node: wave-uniform output-half split (half = (wave&1) via readfirstlane)
__global__ void __launch_bounds__(256,4) k_linear_h(const float* __restrict__ xi, const float* __restrict__ wT,
                           const float* __restrict__ atts, const float* __restrict__ attd,
                           float* __restrict__ h, float* __restrict__ ssc, float* __restrict__ dsc, int N){
  int w = threadIdx.x>>6;
  int half = __builtin_amdgcn_readfirstlane(w & 1);   // SGPR -> weight addrs stay scalar
  int lane = threadIdx.x & 63;
  int nl = (w>>1)*64 + lane;          // 0..127 node-in-block
  int n = blockIdx.x*128 + nl;
  __shared__ float sh_s[128][2], sh_d[128][2];
  float sa=0.f, da=0.f;
  if (n<N){
    float xv[H_];
    const float4* xr = (const float4*)(xi + (size_t)n*H_);
    #pragma unroll
    for(int q=0;q<H_/4;q++){ float4 v=xr[q]; xv[4*q]=v.x; xv[4*q+1]=v.y; xv[4*q+2]=v.z; xv[4*q+3]=v.w; }
    int jb = half*32;
    for(int j0=0;j0<32;j0+=4){
      float o[4];
      #pragma unroll
      for(int jj=0;jj<4;jj++){
        int j = jb + j0 + jj;
        const float* wr = wT + j*H_;   // uniform
        float acc=0.f;
        #pragma unroll
        for(int k=0;k<H_;k++) acc += xv[k]*wr[k];
        o[jj]=acc;
        sa += acc*atts[j]; da += acc*attd[j];
      }
      *(float4*)(h + (size_t)n*H_ + jb + j0) = make_float4(o[0],o[1],o[2],o[3]);
    }
  }
  sh_s[nl][half]=sa; sh_d[nl][half]=da;
  __syncthreads();
  if (half==0 && n<N){
    ssc[n] = sh_s[nl][0]+sh_s[nl][1];
    dsc[n] = sh_d[nl][0]+sh_d[nl][1];
  }
}

// wave per node: segment softmax + weighted aggregation
__global__ void k_gat(const float* __restrict__ h, const float* __restrict__ ssc,
                      const float* __restrict__ dsc, const float* __restrict__ escore,
                      const int* __restrict__ off, const int* __restrict__ eid,
                      const int* __restrict__ srcarr, const float* __restrict__ bias,
                      float* __restrict__ hgat, int E, int N){
  int gid = blockIdx.x*blockDim.x + threadIdx.x;
  int node = gid >> 6;
  int lane = threadIdx.x & 63;
  if (node >= N) return;
  int e0 = off[node], e1 = off[node+1];
  float dval = dsc[node];
  // pass 1: max over incoming edges (lane-parallel)
  float mx = -1e30f;
  for (int p = e0 + lane; p < e1; p += 64) {
    int e = eid[p];
    int s = (e < E) ? srcarr[e] : (e - E);
    float a = ssc[s] + dval + escore[e];
    a = (a > 0.f) ? a : SLOPE*a;
    mx = fmaxf(mx, a);
  }
  #pragma unroll
  for (int d=32; d; d>>=1) mx = fmaxf(mx, __shfl_xor(mx, d));
  // pass 2: serial over edges, lanes = feature dims
  float acc = 0.f, den = 0.f;
  for (int p = e0; p < e1; p++) {
    int e = eid[p];
    int s = (e < E) ? srcarr[e] : (e - E);
    float a = ssc[s] + dval + escore[e];
    a = (a > 0.f) ? a : SLOPE*a;
    float ex = __expf(a - mx);
    den += ex;
    acc += ex * h[(size_t)s*H_ + lane];
  }
  hgat[(size_t)node*H_ + lane] = fmaxf(acc/den + bias[lane], 0.f);
}

// fused GRU cell + relu. Output-half split across blockIdx.y (uniform -> scalar weight loads).
// Reads xin, writes xout (ping-pong; no in-place hazard).
__global__ void __launch_bounds__(256,3) k_gru(const float* __restrict__ hg, const float* __restrict__ xin,
                     float* __restrict__ xout,
                     const float* __restrict__ WihT, const float* __restrict__ WhhT,
                     const float* __restrict__ bih, const float* __restrict__ bhh, int N){
  int n = blockIdx.x*blockDim.x + threadIdx.x;
  if (n>=N) return;
  int jb = blockIdx.y*32;     // output half, uniform
  float hv[H_], xv[H_];
  const float4* hr = (const float4*)(hg + (size_t)n*H_);
  const float4* xr = (const float4*)(xin + (size_t)n*H_);
  #pragma unroll
  for(int q=0;q<H_/4;q++){
    float4 v=hr[q]; hv[4*q]=v.x; hv[4*q+1]=v.y; hv[4*q+2]=v.z; hv[4*q+3]=v.w;
    float4 u=xr[q]; xv[4*q]=u.x; xv[4*q+1]=u.y; xv[4*q+2]=u.z; xv[4*q+3]=u.w;
  }
  for(int j0=0;j0<32;j0+=4){
    float4 xin4 = *(const float4*)(xin + (size_t)n*H_ + jb + j0);  // blend values (static idx)
    const float* xp = (const float*)&xin4;
    float o[4];
    #pragma unroll
    for(int jj=0;jj<4;jj++){
      int j = jb + j0 + jj;
      float gir=bih[j], giz=bih[H_+j], gin=bih[2*H_+j];
      float ghr=bhh[j], ghz=bhh[H_+j], ghn=bhh[2*H_+j];
      const float* wir = WihT + (size_t)j*H_;
      const float* wiz = WihT + (size_t)(H_+j)*H_;
      const float* win = WihT + (size_t)(2*H_+j)*H_;
      const float* whr = WhhT + (size_t)j*H_;
      const float* whz = WhhT + (size_t)(H_+j)*H_;
      const float* whn = WhhT + (size_t)(2*H_+j)*H_;
      #pragma unroll
      for(int k=0;k<H_;k++){
        float hk=hv[k], xk=xv[k];
        gir += hk*wir[k]; giz += hk*wiz[k]; gin += hk*win[k];
        ghr += xk*whr[k]; ghz += xk*whz[k]; ghn += xk*whn[k];
      }
      float r = sigm_(gir+ghr);
      float z = sigm_(giz+ghz);
      float nn = tanh_(gin + r*ghn);
      o[jj] = fmaxf((1.f-z)*nn + z*xp[jj], 0.f);
    }
    *(float4*)(xout + (size_t)n*H_ + jb + j0) = make_float4(o[0],o[1],o[2],o[3]);
  }
}

__global__ void k_pool_init(float* __restrict__ out, const float* __restrict__ b_out, int G){
  int g = blockIdx.x*blockDim.x+threadIdx.x;
  if (g<G) out[g] = b_out[0];
}

__global__ void k_pool(const float* __restrict__ xi, const float* __restrict__ wout,
                       const int* __restrict__ batch, float* __restrict__ out, int N){
  int n = blockIdx.x*blockDim.x+threadIdx.x;
  if (n>=N) return;
  float acc=0.f;
  const float4* xr=(const float4*)(xi + (size_t)n*H_);
  #pragma unroll
  for(int q=0;q<H_/4;q++){
    float4 v=xr[q];
    acc += v.x*wout[4*q] + v.y*wout[4*q+1] + v.z*wout[4*q+2] + v.w*wout[4*q+3];
  }
  atomicAdd(&out[batch[n]], acc);
}

extern "C" void kernel_launch(void* const* d_in, const int* in_sizes, int n_in,
                              void* d_out, int out_size, void* d_ws, size_t ws_size,
                              hipStream_t stream){
  const float* x       = (const float*)d_in[0];
  const float* eattr   = (const float*)d_in[1];
  const float* w_node  = (const float*)d_in[2];
  const float* b_node  = (const float*)d_in[3];
  const float* w_edge  = (const float*)d_in[4];
  const float* b_edge  = (const float*)d_in[5];
  const float* conv_W  = (const float*)d_in[6];
  const float* conv_We = (const float*)d_in[7];
  const float* att_s   = (const float*)d_in[8];
  const float* att_d   = (const float*)d_in[9];
  const float* att_e   = (const float*)d_in[10];
  const float* conv_b  = (const float*)d_in[11];
  const float* gWih    = (const float*)d_in[12];
  const float* gWhh    = (const float*)d_in[13];
  const float* gbih    = (const float*)d_in[14];
  const float* gbhh    = (const float*)d_in[15];
  const float* w_out   = (const float*)d_in[16];
  const float* b_out   = (const float*)d_in[17];
  const int*   eidx    = (const int*)d_in[18];
  const int*   batch   = (const int*)d_in[19];
  float* out = (float*)d_out;

  int N = in_sizes[0]/DIN;
  int E = in_sizes[1]/DE;
  int G = out_size;
  int EN = E + N;
  const int* src = eidx;
  const int* dst = eidx + E;

  char* p = (char*)d_ws;
  auto carve = [&](size_t bytes)->void*{ void* r=(void*)p; p += (bytes+255)&~(size_t)255; return r; };
  float* xi0   = (float*)carve((size_t)N*H_*4);
  float* xi1   = (float*)carve((size_t)N*H_*4);
  float* hbuf  = (float*)carve((size_t)N*H_*4);
  float* hgat  = (float*)carve((size_t)N*H_*4);
  float* ssc   = (float*)carve((size_t)N*4);
  float* dsc   = (float*)carve((size_t)N*4);
  float* escore= (float*)carve((size_t)3*EN*4);
  float* ssum  = (float*)carve((size_t)3*N*4);
  int*   deg   = (int*)carve((size_t)N*4);
  int*   off   = (int*)carve((size_t)(N+1)*4);
  int*   cur   = (int*)carve((size_t)(N+1)*4);
  int*   eid   = (int*)carve((size_t)EN*4);
  int*   bsum  = (int*)carve((size_t)1024*4);
  int*   boff  = (int*)carve((size_t)1024*4);
  float* wnT   = (float*)carve((size_t)DIN*H_*4);
  float* weT   = (float*)carve((size_t)DE*H_*4);
  float* cWT   = (float*)carve((size_t)3*H_*H_*4);
  float* WihT  = (float*)carve((size_t)3*H_*3*H_*4);
  float* WhhT  = (float*)carve((size_t)3*H_*3*H_*4);
  float* ve    = (float*)carve((size_t)3*H_*4);

  auto cdiv=[](int a,int b){return (a+b-1)/b;};
  int NB = cdiv(N,256);   // 391 <= 1024

  k_transpose<<<cdiv(DIN*H_,256),256,0,stream>>>(w_node, wnT, 1, DIN, H_);
  k_transpose<<<cdiv(DE*H_,256),256,0,stream>>>(w_edge, weT, 1, DE, H_);
  k_transpose<<<cdiv(3*H_*H_,256),256,0,stream>>>(conv_W, cWT, 3, H_, H_);
  k_transpose<<<cdiv(3*H_*3*H_,256),256,0,stream>>>(gWih, WihT, 3, H_, 3*H_);
  k_transpose<<<cdiv(3*H_*3*H_,256),256,0,stream>>>(gWhh, WhhT, 3, H_, 3*H_);
  k_ve<<<1,3*H_,0,stream>>>(conv_We, att_e, ve);

  k_init<<<cdiv(N,256),256,0,stream>>>(deg, ssum, N);
  k_node_mlp<<<cdiv(N,256),256,0,stream>>>(x, wnT, b_node, xi0, N);
  k_edge_scores<<<cdiv(E,256),256,0,stream>>>(eattr, weT, b_edge, ve, dst, escore, ssum, deg, E, EN, N);
  k_selfloop<<<cdiv(N,256),256,0,stream>>>(ssum, deg, escore, E, EN, N);
  k_bsum<<<NB,256,0,stream>>>(deg, bsum, N);
  k_bscan<<<1,1024,0,stream>>>(bsum, boff, NB, off+N, EN);
  k_scan_fin<<<NB,256,0,stream>>>(deg, boff, off, cur, N);
  k_fill<<<cdiv(EN,256),256,0,stream>>>(dst, cur, eid, E, N);

  for (int l=0; l<3; l++){
    const float* xin = (l&1) ? xi1 : xi0;
    float*       xo  = (l&1) ? xi0 : xi1;
    k_linear_h<<<cdiv(N,128),256,0,stream>>>(xin, cWT + (size_t)l*H_*H_, att_s + l*H_, att_d + l*H_,
                                             hbuf, ssc, dsc, N);
    k_gat<<<cdiv(N*64,256),256,0,stream>>>(hbuf, ssc, dsc, escore + (size_t)l*EN, off, eid, src,
                                           conv_b + l*H_, hgat, E, N);
    k_gru<<<dim3(cdiv(N,256),2),256,0,stream>>>(hgat, xin, xo, WihT + (size_t)l*3*H_*H_, WhhT + (size_t)l*3*H_*H_,
                                                gbih + l*3*H_, gbhh + l*3*H_, N);
  }

  k_pool_init<<<cdiv(G,256),256,0,stream>>>(out, b_out, G);
  k_pool<<<cdiv(N,256),256,0,stream>>>(xi1, w_out, batch, out, N);
}